// Round 3
// baseline (151.285 us; speedup 1.0000x reference)
//
#include <hip/hip_runtime.h>

// Fused quantized 3x3 conv, stride 1, pad 1:
//   x: [32,64,112,112] fp32 -> uint4-range [0,15] (quantized on the fly)
//   w: [128,64,3,3]    fp32 -> int4-range [-8,7]  (k_quant_w -> wq in d_ws)
//   out: [32,128,112,112] fp32 (integer-exact)
//
// k_fused: per block, stage+quantize an 8x16 spatial tile (+1 halo -> 10x18)
// of all 64 input channels into LDS as int8 [r][w][c] (c-dim padded to 80 B
// for aligned, conflict-free ds_read_b128), then implicit-GEMM with
// v_mfma_i32_16x16x64_i8. Weights come straight from global (73.7 KB, L2-hot),
// so no weight LDS, no inner barrier, 4 blocks/CU.

#define CIN  64
#define HH   112
#define WW   112
#define COUT 128
#define KTOT 576            // 64*3*3

#define TR 8                // output tile rows per block
#define TC 16               // output tile cols per block
#define HR 10               // halo rows
#define HC 18               // halo cols
#define CP 80               // padded channel bytes (64 used) -> 16B-aligned reads
#define ROWB (HC * CP)      // 1440 bytes per tile row
#define NSTAGE (HR * HC * CIN)   // 11520 elements

typedef __attribute__((ext_vector_type(4))) int int32x4;

__global__ void k_quant_w(const float* __restrict__ w, char* __restrict__ wq) {
    int idx = blockIdx.x * 256 + threadIdx.x;       // 73728 total
    int o  = idx / KTOT;
    int r  = idx % KTOT;
    int kh = r / 192;
    int kw = (r / 64) % 3;
    int c  = r % 64;
    float v = w[((o * CIN + c) * 3 + kh) * 3 + kw];
    float q = fminf(fmaxf(rintf(v), -8.0f), 7.0f);   // RTNE == jnp.round
    wq[idx] = (char)(int)q;
}

__global__ __launch_bounds__(256, 4) void k_fused(const float* __restrict__ x,
                                                  const char* __restrict__ wq,
                                                  float* __restrict__ out) {
    __shared__ char xs[HR * ROWB];   // 14,400 B

    const int tid = threadIdx.x;
    const int bw = blockIdx.x, bh = blockIdx.y, n = blockIdx.z;
    const int h0 = bh * TR, w0 = bw * TC;

    const float* xn = x + (size_t)n * CIN * HH * WW;

    // Stage + quantize the halo tile. Lane mapping w-fastest -> coalesced
    // fp32 reads (72 B row segments); byte LDS writes.
    for (int e = tid; e < NSTAGE; e += 256) {
        int c   = e / (HR * HC);
        int rem = e - c * (HR * HC);
        int r   = rem / HC;
        int wc  = rem - r * HC;
        int gh = h0 - 1 + r;
        int gw = w0 - 1 + wc;
        float v = 0.0f;
        if ((unsigned)gh < HH && (unsigned)gw < WW)
            v = xn[((size_t)c * HH + gh) * WW + gw];
        float q = fminf(fmaxf(rintf(v), 0.0f), 15.0f);
        xs[r * ROWB + wc * CP + c] = (char)(int)q;
    }
    __syncthreads();

    const int wave = tid >> 6;
    const int lane = tid & 63;
    const int l15  = lane & 15;
    const int lk   = lane >> 4;      // 16-byte k-chunk within 64 channels
    const int spg  = wave >> 1;      // spatial group: rows spg*4 .. spg*4+3
    const int cog  = wave & 1;       // cout group: cog*64 .. +63
    const int cobase = cog * 64;

    // Per-lane weight base: row (cobase + tO*16 + l15), k-chunk lk
    const char* wp0 = wq + (size_t)(cobase + l15) * KTOT + lk * 16;

    int32x4 acc[4][4];   // [tS][tO]
#pragma unroll
    for (int i = 0; i < 4; ++i)
#pragma unroll
        for (int j = 0; j < 4; ++j) acc[i][j] = (int32x4)(0);

    // A-frag base: tile row (spg*4 + tS + kh), w-index (l15 + kw), chunk lk
    const int abase = (spg * 4) * ROWB + l15 * CP + lk * 16;

#pragma unroll
    for (int ks = 0; ks < 9; ++ks) {
        const int kh = ks / 3, kw = ks % 3;
        const int aoff = abase + kh * ROWB + kw * CP;
        int32x4 af[4];
#pragma unroll
        for (int tS = 0; tS < 4; ++tS)
            af[tS] = *(const int32x4*)(&xs[aoff + tS * ROWB]);
#pragma unroll
        for (int tO = 0; tO < 4; ++tO) {
            int32x4 bf = *(const int32x4*)(wp0 + tO * 16 * KTOT + ks * 64);
#pragma unroll
            for (int tS = 0; tS < 4; ++tS)
                acc[tS][tO] = __builtin_amdgcn_mfma_i32_16x16x64_i8(af[tS], bf, acc[tS][tO], 0, 0, 0);
        }
    }

    // Epilogue: D col = l15 -> cout, row = lk*4 + reg -> spatial w (consecutive)
#pragma unroll
    for (int tS = 0; tS < 4; ++tS) {
        const int gh = h0 + spg * 4 + tS;
#pragma unroll
        for (int tO = 0; tO < 4; ++tO) {
            const int co = cobase + tO * 16 + l15;
            float4 v;
            v.x = (float)acc[tS][tO][0];
            v.y = (float)acc[tS][tO][1];
            v.z = (float)acc[tS][tO][2];
            v.w = (float)acc[tS][tO][3];
            *(float4*)(&out[(((size_t)n * COUT + co) * HH + gh) * WW + w0 + lk * 4]) = v;
        }
    }
}

extern "C" void kernel_launch(void* const* d_in, const int* in_sizes, int n_in,
                              void* d_out, int out_size, void* d_ws, size_t ws_size,
                              hipStream_t stream) {
    const float* x = (const float*)d_in[0];
    const float* w = (const float*)d_in[1];
    float* out = (float*)d_out;

    char* wq = (char*)d_ws;   // 73,728 B

    hipLaunchKernelGGL(k_quant_w, dim3((COUT * KTOT) / 256), dim3(256), 0, stream, w, wq);
    hipLaunchKernelGGL(k_fused, dim3(WW / TC, HH / TR, 32), dim3(256), 0, stream,
                       x, wq, out);
}